// Round 8
// baseline (286.424 us; speedup 1.0000x reference)
//
#include <hip/hip_runtime.h>
#include <stdint.h>

#define SEQ   2048
#define BATCH 4
#define NH    16
#define HD    64
#define DIMN  1024
#define MROWS (BATCH*SEQ)   // 8192

typedef __attribute__((ext_vector_type(8)))  short          bf16x8;
typedef __attribute__((ext_vector_type(8)))  unsigned short ushort8;
typedef __attribute__((ext_vector_type(4)))  float          f32x4;
typedef __attribute__((ext_vector_type(16))) float          f32x16;

static __device__ __forceinline__ unsigned short f2bf(float f) {
    unsigned int u = __builtin_bit_cast(unsigned int, f);
    u += 0x7fffu + ((u >> 16) & 1u);          // RNE
    return (unsigned short)(u >> 16);
}
// RNE-ish (round-half-up) pack: 3 ops
static __device__ __forceinline__ unsigned int pack2bf(float lo, float hi) {
    unsigned int a = __builtin_bit_cast(unsigned int, lo) + 0x8000u;
    unsigned int b = __builtin_bit_cast(unsigned int, hi) + 0x8000u;
    return __builtin_amdgcn_perm(b, a, 0x07060302u);
}
// truncating pack: 1 op (P in [0,1], rel err <= 2^-8, fine for softmax weights)
static __device__ __forceinline__ unsigned int pack2bf_trunc(float lo, float hi) {
    return __builtin_amdgcn_perm(__builtin_bit_cast(unsigned int, hi),
                                 __builtin_bit_cast(unsigned int, lo), 0x07060302u);
}

// ---------------------------------------------------------------- fused prologue
__global__ __launch_bounds__(256) void prologue_kernel(
        const float* __restrict__ x,
        const float* __restrict__ qw, const float* __restrict__ kw,
        const float* __restrict__ vw, const float* __restrict__ ow,
        unsigned short* __restrict__ xb,
        unsigned short* __restrict__ wq, unsigned short* __restrict__ wk,
        unsigned short* __restrict__ wv, unsigned short* __restrict__ wo,
        float* __restrict__ cosT, float* __restrict__ sinT,
        const unsigned char* __restrict__ mask, unsigned long long* __restrict__ m64) {
    const int bx = blockIdx.x, tid = threadIdx.x;
    if (bx < 4096 + 2048) {
        const float* s; unsigned short* d; int i;
        if (bx < 4096) { s = x; d = xb; i = bx * 2048 + tid * 8; }
        else {
            int wb = bx - 4096;
            int wsel = wb >> 9;
            s = wsel == 0 ? qw : (wsel == 1 ? kw : (wsel == 2 ? vw : ow));
            d = wsel == 0 ? wq : (wsel == 1 ? wk : (wsel == 2 ? wv : wo));
            i = (wb & 511) * 2048 + tid * 8;
        }
        float4 a = *(const float4*)(s + i);
        float4 b = *(const float4*)(s + i + 4);
        ushort8 o;
        o[0]=f2bf(a.x); o[1]=f2bf(a.y); o[2]=f2bf(a.z); o[3]=f2bf(a.w);
        o[4]=f2bf(b.x); o[5]=f2bf(b.y); o[6]=f2bf(b.z); o[7]=f2bf(b.w);
        *(ushort8*)(d + i) = o;
    } else if (bx < 6400) {
        int idx = (bx - 6144) * 256 + tid;        // SEQ*32
        int s = idx >> 5, j = idx & 31;
        float t = (float)(2 * j) / 64.0f;
        float freq = 1.0f / powf(10000.0f, t);
        float ang  = (float)s * freq;
        cosT[idx] = cosf(ang);
        sinT[idx] = sinf(ang);
    } else {
        if (tid < 128) {
            int b = tid >> 5, kt = tid & 31;
            const unsigned char* p = mask + b * SEQ + kt * 64;
            unsigned long long v = 0;
            for (int j = 0; j < 64; j++) v |= (unsigned long long)(p[j] != 0) << j;
            m64[tid] = v;
        }
    }
}

// ---------------------------------------------------------------- merged Q+K GEMM
// v4: Q and K share the A-tile (X). One block stages X + Wq + Wk (3 tiles,
// dbuf = 48 KiB LDS) and each wave computes a 64x64 tile of BOTH outputs:
// 12 ds_read_b128 : 32 MFMA per K-step (0.375 DS/MFMA vs 0.5 split), X
// traffic halved, barrier drain amortized over 2x MFMA. acc = 128 AGPR ->
// (256,2) caps at 256 regs, 2 blocks/CU (same ~20% occupancy as before).
__global__ __launch_bounds__(256, 2) void gemm_qk(const unsigned short* __restrict__ X,
        const unsigned short* __restrict__ Wq, const unsigned short* __restrict__ Wk,
        const float* __restrict__ bq, const float* __restrict__ bk,
        unsigned short* __restrict__ Qo, unsigned short* __restrict__ Ko,
        const float* __restrict__ cosT, const float* __restrict__ sinT) {
    __shared__ __align__(16) unsigned short As0[128 * 32];
    __shared__ __align__(16) unsigned short Bq0[128 * 32];
    __shared__ __align__(16) unsigned short Bk0[128 * 32];
    __shared__ __align__(16) unsigned short As1[128 * 32];
    __shared__ __align__(16) unsigned short Bq1[128 * 32];
    __shared__ __align__(16) unsigned short Bk1[128 * 32];
    const int tid  = threadIdx.x;
    const int wid  = tid >> 6, lane = tid & 63;
    const int quad = lane >> 4, l15 = lane & 15;
    const int wm   = wid >> 1,  wn  = wid & 1;
    const int m0   = blockIdx.y * 128;          // token rows
    const int n0   = blockIdx.x * 128;          // embed cols

    f32x4 aq[4][4], ak[4][4];
#pragma unroll
    for (int i = 0; i < 4; i++)
#pragma unroll
        for (int j = 0; j < 4; j++) { aq[i][j] = (f32x4)0.0f; ak[i][j] = (f32x4)0.0f; }

    const int rb = wid * 32 + (lane >> 2);
    const int cb = (((lane & 3) ^ ((lane >> 3) & 3)) * 8);
    const int rq = (quad ^ ((l15 >> 1) & 3)) * 8;

#define QKSTAGE(AS, BQ, BK, KK) do {                                                        \
    _Pragma("unroll")                                                                       \
    for (int i_ = 0; i_ < 2; i_++) {                                                        \
        const unsigned short* ga_ = X  + (size_t)(m0 + rb + i_ * 16) * DIMN + (KK) + cb;    \
        __builtin_amdgcn_global_load_lds((const __attribute__((address_space(1))) void*)ga_,\
            (__attribute__((address_space(3))) void*)&AS[(wid * 32 + i_ * 16) * 32], 16, 0, 0);\
        const unsigned short* gq_ = Wq + (size_t)(n0 + rb + i_ * 16) * DIMN + (KK) + cb;    \
        __builtin_amdgcn_global_load_lds((const __attribute__((address_space(1))) void*)gq_,\
            (__attribute__((address_space(3))) void*)&BQ[(wid * 32 + i_ * 16) * 32], 16, 0, 0);\
        const unsigned short* gk_ = Wk + (size_t)(n0 + rb + i_ * 16) * DIMN + (KK) + cb;    \
        __builtin_amdgcn_global_load_lds((const __attribute__((address_space(1))) void*)gk_,\
            (__attribute__((address_space(3))) void*)&BK[(wid * 32 + i_ * 16) * 32], 16, 0, 0);\
    } } while (0)

#define QKCOMP(AS, BQ, BK) do {                                                             \
    bf16x8 af_[4], bqf_[4], bkf_[4];                                                        \
    _Pragma("unroll")                                                                       \
    for (int f_ = 0; f_ < 4; f_++) af_[f_]  = *(const bf16x8*)&AS[(wm * 64 + f_ * 16 + l15) * 32 + rq]; \
    _Pragma("unroll")                                                                       \
    for (int f_ = 0; f_ < 4; f_++) bqf_[f_] = *(const bf16x8*)&BQ[(wn * 64 + f_ * 16 + l15) * 32 + rq]; \
    _Pragma("unroll")                                                                       \
    for (int f_ = 0; f_ < 4; f_++) bkf_[f_] = *(const bf16x8*)&BK[(wn * 64 + f_ * 16 + l15) * 32 + rq]; \
    _Pragma("unroll")                                                                       \
    for (int fm_ = 0; fm_ < 4; fm_++)                                                       \
        _Pragma("unroll")                                                                   \
        for (int fn_ = 0; fn_ < 4; fn_++) {                                                 \
            aq[fm_][fn_] = __builtin_amdgcn_mfma_f32_16x16x32_bf16(af_[fm_], bqf_[fn_], aq[fm_][fn_], 0, 0, 0); \
            ak[fm_][fn_] = __builtin_amdgcn_mfma_f32_16x16x32_bf16(af_[fm_], bkf_[fn_], ak[fm_][fn_], 0, 0, 0); \
        } } while (0)

    QKSTAGE(As0, Bq0, Bk0, 0);
    for (int k0 = 0; k0 < DIMN; k0 += 64) {
        __syncthreads();                           // buf0 ready
        QKSTAGE(As1, Bq1, Bk1, k0 + 32);
        QKCOMP(As0, Bq0, Bk0);
        __syncthreads();                           // buf1 ready
        if (k0 + 64 < DIMN) QKSTAGE(As0, Bq0, Bk0, k0 + 64);
        QKCOMP(As1, Bq1, Bk1);
    }
#undef QKSTAGE
#undef QKCOMP

    const int h = (n0 >> 6) + wn;
#define QKEPI(ACC, BIAS, OUT, SCALE) do {                                                   \
    float bv4_[4];                                                                          \
    _Pragma("unroll")                                                                       \
    for (int fn_ = 0; fn_ < 4; fn_++) bv4_[fn_] = BIAS[n0 + wn * 64 + fn_ * 16 + l15];      \
    _Pragma("unroll")                                                                       \
    for (int fm_ = 0; fm_ < 4; fm_++)                                                       \
        _Pragma("unroll")                                                                   \
        for (int r_ = 0; r_ < 4; r_++) {                                                    \
            int mrow_ = m0 + wm * 64 + fm_ * 16 + quad * 4 + r_;                            \
            int b_ = mrow_ >> 11, s_ = mrow_ & (SEQ - 1);                                   \
            unsigned short* orow_ = OUT + ((size_t)(b_ * NH + h) * SEQ + s_) * HD;          \
            float v0_ = (ACC[fm_][0][r_] + bv4_[0]) * (SCALE);                              \
            float v1_ = (ACC[fm_][1][r_] + bv4_[1]) * (SCALE);                              \
            float v2_ = (ACC[fm_][2][r_] + bv4_[2]) * (SCALE);                              \
            float v3_ = (ACC[fm_][3][r_] + bv4_[3]) * (SCALE);                              \
            int d0_ = l15, d1_ = 16 + l15;                                                  \
            float c0_ = cosT[s_ * 32 + d0_], s0_ = sinT[s_ * 32 + d0_];                     \
            float c1_ = cosT[s_ * 32 + d1_], s1_ = sinT[s_ * 32 + d1_];                     \
            orow_[d0_]      = f2bf(v0_ * c0_ - v2_ * s0_);                                  \
            orow_[d0_ + 32] = f2bf(v0_ * s0_ + v2_ * c0_);                                  \
            orow_[d1_]      = f2bf(v1_ * c1_ - v3_ * s1_);                                  \
            orow_[d1_ + 32] = f2bf(v1_ * s1_ + v3_ * c1_);                                  \
        } } while (0)

    QKEPI(aq, bq, Qo, 0.18033688011112042f);      // 0.125*log2e
    QKEPI(ak, bk, Ko, 1.0f);
#undef QKEPI
}

// ---------------------------------------------------------------- V^T GEMM
// (old gemm_qkvt which==2 path, verbatim structure) out [B,H,D,S]
__global__ __launch_bounds__(256) void gemm_vt(const unsigned short* __restrict__ Wv,
        const unsigned short* __restrict__ X, const float* __restrict__ bv,
        unsigned short* __restrict__ Vto) {
    __shared__ __align__(16) unsigned short As0[128 * 32];
    __shared__ __align__(16) unsigned short Bs0[128 * 32];
    __shared__ __align__(16) unsigned short As1[128 * 32];
    __shared__ __align__(16) unsigned short Bs1[128 * 32];
    const int tid  = threadIdx.x;
    const int wid  = tid >> 6, lane = tid & 63;
    const int quad = lane >> 4, l15 = lane & 15;
    const int wm   = wid >> 1,  wn  = wid & 1;
    const int m0   = blockIdx.x * 128;          // e rows
    const int n0   = blockIdx.y * 128;          // token rows

    f32x4 acc[4][4];
#pragma unroll
    for (int i = 0; i < 4; i++)
#pragma unroll
        for (int j = 0; j < 4; j++) acc[i][j] = (f32x4)0.0f;

    const int rb = wid * 32 + (lane >> 2);
    const int cb = (((lane & 3) ^ ((lane >> 3) & 3)) * 8);
    const int rq = (quad ^ ((l15 >> 1) & 3)) * 8;

#define GSTAGE(BA, BB, KK) do {                                                             \
    _Pragma("unroll")                                                                       \
    for (int i_ = 0; i_ < 2; i_++) {                                                        \
        const unsigned short* ga_ = Wv + (size_t)(m0 + rb + i_ * 16) * DIMN + (KK) + cb;    \
        __builtin_amdgcn_global_load_lds((const __attribute__((address_space(1))) void*)ga_,\
            (__attribute__((address_space(3))) void*)&BA[(wid * 32 + i_ * 16) * 32], 16, 0, 0);\
        const unsigned short* gb_ = X + (size_t)(n0 + rb + i_ * 16) * DIMN + (KK) + cb;     \
        __builtin_amdgcn_global_load_lds((const __attribute__((address_space(1))) void*)gb_,\
            (__attribute__((address_space(3))) void*)&BB[(wid * 32 + i_ * 16) * 32], 16, 0, 0);\
    } } while (0)

#define GCOMP(BA, BB) do {                                                                  \
    bf16x8 af_[4], bf_[4];                                                                  \
    _Pragma("unroll")                                                                       \
    for (int f_ = 0; f_ < 4; f_++) af_[f_] = *(const bf16x8*)&BA[(wm * 64 + f_ * 16 + l15) * 32 + rq]; \
    _Pragma("unroll")                                                                       \
    for (int f_ = 0; f_ < 4; f_++) bf_[f_] = *(const bf16x8*)&BB[(wn * 64 + f_ * 16 + l15) * 32 + rq]; \
    _Pragma("unroll")                                                                       \
    for (int fm_ = 0; fm_ < 4; fm_++)                                                       \
        _Pragma("unroll")                                                                   \
        for (int fn_ = 0; fn_ < 4; fn_++)                                                   \
            acc[fm_][fn_] = __builtin_amdgcn_mfma_f32_16x16x32_bf16(af_[fm_], bf_[fn_], acc[fm_][fn_], 0, 0, 0); \
    } while (0)

    GSTAGE(As0, Bs0, 0);
    for (int k0 = 0; k0 < DIMN; k0 += 64) {
        __syncthreads();
        GSTAGE(As1, Bs1, k0 + 32);
        GCOMP(As0, Bs0);
        __syncthreads();
        if (k0 + 64 < DIMN) GSTAGE(As0, Bs0, k0 + 64);
        GCOMP(As1, Bs1);
    }

    float4 bb[4];
#pragma unroll
    for (int fm = 0; fm < 4; fm++)
        bb[fm] = *(const float4*)&bv[m0 + wm * 64 + fm * 16 + quad * 4];
    const int b     = n0 >> 11;
    const int sbase = (n0 & (SEQ - 1)) + wn * 64 + l15;
#pragma unroll
    for (int fm = 0; fm < 4; fm++)
#pragma unroll
        for (int r = 0; r < 4; r++) {
            int e = m0 + wm * 64 + fm * 16 + quad * 4 + r;
            float bval = r == 0 ? bb[fm].x : (r == 1 ? bb[fm].y : (r == 2 ? bb[fm].z : bb[fm].w));
            unsigned short* row = Vto + ((size_t)(b * NH + (e >> 6)) * HD + (e & 63)) * SEQ + sbase;
#pragma unroll
            for (int fn = 0; fn < 4; fn++)
                row[fn * 16] = f2bf(acc[fm][fn][r] + bval);
        }
#undef GSTAGE
#undef GCOMP
}

// ---------------------------------------------------------------- output-proj GEMM (fp32 out)
__global__ __launch_bounds__(256) void gemm_bt(const unsigned short* __restrict__ A,
                                               const unsigned short* __restrict__ W,
                                               const float* __restrict__ bias,
                                               float* __restrict__ out) {
    __shared__ __align__(16) unsigned short As0[128 * 32];
    __shared__ __align__(16) unsigned short Bs0[128 * 32];
    __shared__ __align__(16) unsigned short As1[128 * 32];
    __shared__ __align__(16) unsigned short Bs1[128 * 32];
    const int tid  = threadIdx.x;
    const int wid  = tid >> 6, lane = tid & 63;
    const int quad = lane >> 4, l15 = lane & 15;
    const int wm   = wid >> 1,  wn  = wid & 1;
    const int m0   = blockIdx.y * 128, n0 = blockIdx.x * 128;

    f32x4 acc[4][4];
#pragma unroll
    for (int i = 0; i < 4; i++)
#pragma unroll
        for (int j = 0; j < 4; j++) acc[i][j] = (f32x4)0.0f;

    const int rb = wid * 32 + (lane >> 2);
    const int cb = (((lane & 3) ^ ((lane >> 3) & 3)) * 8);
    const int rq = (quad ^ ((l15 >> 1) & 3)) * 8;

#define GSTAGE(BA, BB, KK) do {                                                             \
    _Pragma("unroll")                                                                       \
    for (int i_ = 0; i_ < 2; i_++) {                                                        \
        const unsigned short* ga_ = A + (size_t)(m0 + rb + i_ * 16) * DIMN + (KK) + cb;     \
        __builtin_amdgcn_global_load_lds((const __attribute__((address_space(1))) void*)ga_,\
            (__attribute__((address_space(3))) void*)&BA[(wid * 32 + i_ * 16) * 32], 16, 0, 0);\
        const unsigned short* gb_ = W + (size_t)(n0 + rb + i_ * 16) * DIMN + (KK) + cb;     \
        __builtin_amdgcn_global_load_lds((const __attribute__((address_space(1))) void*)gb_,\
            (__attribute__((address_space(3))) void*)&BB[(wid * 32 + i_ * 16) * 32], 16, 0, 0);\
    } } while (0)

#define GCOMP(BA, BB) do {                                                                  \
    bf16x8 af_[4], bf_[4];                                                                  \
    _Pragma("unroll")                                                                       \
    for (int f_ = 0; f_ < 4; f_++) af_[f_] = *(const bf16x8*)&BA[(wm * 64 + f_ * 16 + l15) * 32 + rq]; \
    _Pragma("unroll")                                                                       \
    for (int f_ = 0; f_ < 4; f_++) bf_[f_] = *(const bf16x8*)&BB[(wn * 64 + f_ * 16 + l15) * 32 + rq]; \
    _Pragma("unroll")                                                                       \
    for (int fm_ = 0; fm_ < 4; fm_++)                                                       \
        _Pragma("unroll")                                                                   \
        for (int fn_ = 0; fn_ < 4; fn_++)                                                   \
            acc[fm_][fn_] = __builtin_amdgcn_mfma_f32_16x16x32_bf16(af_[fm_], bf_[fn_], acc[fm_][fn_], 0, 0, 0); \
    } while (0)

    GSTAGE(As0, Bs0, 0);
    for (int k0 = 0; k0 < DIMN; k0 += 64) {
        __syncthreads();
        GSTAGE(As1, Bs1, k0 + 32);
        GCOMP(As0, Bs0);
        __syncthreads();
        if (k0 + 64 < DIMN) GSTAGE(As0, Bs0, k0 + 64);
        GCOMP(As1, Bs1);
    }

    float bv4[4];
#pragma unroll
    for (int fn = 0; fn < 4; fn++) bv4[fn] = bias[n0 + wn * 64 + fn * 16 + l15];
#pragma unroll
    for (int fm = 0; fm < 4; fm++)
#pragma unroll
        for (int r = 0; r < 4; r++) {
            int mrow = m0 + wm * 64 + fm * 16 + quad * 4 + r;
            float* orow = out + (size_t)mrow * DIMN + n0 + wn * 64;
#pragma unroll
            for (int fn = 0; fn < 4; fn++) orow[fn * 16 + l15] = acc[fm][fn][r] + bv4[fn];
        }
#undef GSTAGE
#undef GCOMP
}

// ---------------------------------------------------------------- flash attention v13 (revert)
// v14's source-order pipeline was re-serialized by the compiler (VGPR stayed
// 64) and regressed; v13 is the measured-best (90.6 us). 32x32x16 core,
// shuffle-based P redistribution, single-buffered staged tiles.
__global__ __launch_bounds__(256, 4) void attn_kernel(const unsigned short* __restrict__ Q,
                                                      const unsigned short* __restrict__ K,
                                                      const unsigned short* __restrict__ Vt,
                                                      const unsigned long long* __restrict__ M64,
                                                      unsigned short* __restrict__ Ob) {
    __shared__ __align__(16) unsigned short Kls[64 * 64];   // 8 KiB [token][k]
    __shared__ __align__(16) unsigned short Vls[64 * 64];   // 8 KiB [d][token]

    const int tid  = threadIdx.x;
    const int wid  = tid >> 6, lane = tid & 63;
    const int hi   = lane >> 5, l31 = lane & 31, l7 = lane & 7;
    const int bid = blockIdx.x;
    const int bh  = (bid & 7) * 8 + (bid >> 7);
    const int qt  = (bid >> 3) & 15;
    const int b = bh >> 4, h = bh & 15;
    const int q0 = qt * 128;

    bf16x8 qB[4];
    {
        const unsigned short* qrow = Q + ((size_t)bh * SEQ + q0 + wid * 32 + l31) * HD + hi * 8;
#pragma unroll
        for (int ks = 0; ks < 4; ks++)
            qB[ks] = __builtin_bit_cast(bf16x8, *(const uint4*)(qrow + ks * 16));
    }

    f32x16 Oa[2];
    Oa[0] = (f32x16)0.0f;
    Oa[1] = (f32x16)0.0f;
    float ls = 0.0f;

    const unsigned long long* Mrow = M64 + b * (SEQ / 64);

    const int srow = lane >> 3;
    const int sgr  = ((lane & 7) ^ ((lane >> 3) & 7)) * 8;
    const unsigned short* Kg = K  + (size_t)bh * SEQ * HD;
    const unsigned short* Vg = Vt + (size_t)bh * HD * SEQ;
    const unsigned short* Kb0 = Kg + (size_t)(wid * 16 + srow) * HD + sgr;
    const unsigned short* Vb0 = Vg + (size_t)(wid * 16 + srow) * SEQ + sgr;

    for (int kt = 0; kt < SEQ / 64; kt++) {
        const int k0 = kt * 64;
#pragma unroll
        for (int j = 0; j < 2; j++) {
            __builtin_amdgcn_global_load_lds(
                (const __attribute__((address_space(1))) void*)(Kb0 + (size_t)(k0 + j * 8) * HD),
                (__attribute__((address_space(3))) void*)&Kls[(wid * 16 + j * 8) * 64], 16, 0, 0);
            __builtin_amdgcn_global_load_lds(
                (const __attribute__((address_space(1))) void*)(Vb0 + (size_t)(j * 8) * SEQ + k0),
                (__attribute__((address_space(3))) void*)&Vls[(wid * 16 + j * 8) * 64], 16, 0, 0);
        }
        unsigned long long mb = Mrow[kt];
        __syncthreads();

#pragma unroll
        for (int h2 = 0; h2 < 2; h2++) {
            bf16x8 kA[4];
#pragma unroll
            for (int ks = 0; ks < 4; ks++)
                kA[ks] = *(const bf16x8*)&Kls[(h2 * 32 + l31) * 64 + (((ks << 1) + hi) ^ l7) * 8];

            f32x16 st = (f32x16)0.0f;
            __builtin_amdgcn_s_setprio(1);
#pragma unroll
            for (int ks = 0; ks < 4; ks++)
                st = __builtin_amdgcn_mfma_f32_32x32x16_bf16(kA[ks], qB[ks], st, 0, 0, 0);
            __builtin_amdgcn_s_setprio(0);

            unsigned int mh = (unsigned int)(mb >> (h2 * 32));
            if (mh) {
#pragma unroll
                for (int r = 0; r < 16; r++) {
                    int kk = (r & 3) + ((r >> 2) << 3) + (hi << 2);
                    if ((mh >> kk) & 1u) st[r] = -1e9f;
                }
            }

            float p[16];
#pragma unroll
            for (int r = 0; r < 16; r++) p[r] = __builtin_amdgcn_exp2f(st[r]);
            float s01 = (p[0] + p[1]) + (p[2] + p[3]);
            float s23 = (p[4] + p[5]) + (p[6] + p[7]);
            float s45 = (p[8] + p[9]) + (p[10] + p[11]);
            float s67 = (p[12] + p[13]) + (p[14] + p[15]);
            ls += (s01 + s23) + (s45 + s67);

            unsigned int w000 = pack2bf_trunc(p[0],  p[1]);
            unsigned int w001 = pack2bf_trunc(p[2],  p[3]);
            unsigned int w010 = pack2bf_trunc(p[4],  p[5]);
            unsigned int w011 = pack2bf_trunc(p[6],  p[7]);
            unsigned int w100 = pack2bf_trunc(p[8],  p[9]);
            unsigned int w101 = pack2bf_trunc(p[10], p[11]);
            unsigned int w110 = pack2bf_trunc(p[12], p[13]);
            unsigned int w111 = pack2bf_trunc(p[14], p[15]);

            bf16x8 pB[2];
#pragma unroll
            for (int ks = 0; ks < 2; ks++) {
                unsigned int own0 = ks == 0 ? (hi ? w010 : w000) : (hi ? w110 : w100);
                unsigned int own1 = ks == 0 ? (hi ? w011 : w001) : (hi ? w111 : w101);
                unsigned int oth0 = ks == 0 ? (hi ? w000 : w010) : (hi ? w100 : w110);
                unsigned int oth1 = ks == 0 ? (hi ? w001 : w011) : (hi ? w101 : w111);
                unsigned int r0 = (unsigned int)__shfl_xor((int)oth0, 32);
                unsigned int r1 = (unsigned int)__shfl_xor((int)oth1, 32);
                uint4 pw;
                pw.x = hi ? r0 : own0;
                pw.y = hi ? r1 : own1;
                pw.z = hi ? own0 : r0;
                pw.w = hi ? own1 : r1;
                pB[ks] = __builtin_bit_cast(bf16x8, pw);
            }

            __builtin_amdgcn_s_setprio(1);
#pragma unroll
            for (int dt = 0; dt < 2; dt++)
#pragma unroll
                for (int kv = 0; kv < 2; kv++) {
                    bf16x8 vA = *(const bf16x8*)&Vls[(dt * 32 + l31) * 64 +
                                    (((h2 << 2) + (kv << 1) + hi) ^ l7) * 8];
                    Oa[dt] = __builtin_amdgcn_mfma_f32_32x32x16_bf16(vA, pB[kv], Oa[dt], 0, 0, 0);
                }
            __builtin_amdgcn_s_setprio(0);
        }
        __syncthreads();
    }

    float lsum = ls + __shfl_xor(ls, 32);
    float linv = 1.0f / lsum;

    const int s = q0 + wid * 32 + l31;
    unsigned short* orow = Ob + ((size_t)b * SEQ + s) * DIMN + h * HD + hi * 4;
#pragma unroll
    for (int dt = 0; dt < 2; dt++)
#pragma unroll
        for (int rq = 0; rq < 4; rq++) {
            uint2 w;
            w.x = pack2bf(Oa[dt][rq * 4 + 0] * linv, Oa[dt][rq * 4 + 1] * linv);
            w.y = pack2bf(Oa[dt][rq * 4 + 2] * linv, Oa[dt][rq * 4 + 3] * linv);
            *(uint2*)&orow[dt * 32 + rq * 8] = w;
        }
}

// ---------------------------------------------------------------- launch
extern "C" void kernel_launch(void* const* d_in, const int* in_sizes, int n_in,
                              void* d_out, int out_size, void* d_ws, size_t ws_size,
                              hipStream_t stream) {
    (void)in_sizes; (void)n_in; (void)out_size; (void)ws_size;
    const float* x  = (const float*)d_in[0];
    const unsigned char* mask = (const unsigned char*)d_in[1];
    const float* q_w = (const float*)d_in[2];
    const float* q_b = (const float*)d_in[3];
    const float* k_w = (const float*)d_in[4];
    const float* k_b = (const float*)d_in[5];
    const float* v_w = (const float*)d_in[6];
    const float* v_b = (const float*)d_in[7];
    const float* o_w = (const float*)d_in[8];
    const float* o_b = (const float*)d_in[9];
    float* out = (float*)d_out;

    char* w = (char*)d_ws;
    unsigned short* xb = (unsigned short*)w;                        // 16 MiB (reused as attn output)
    unsigned short* wq = (unsigned short*)(w + (16u << 20));        // 4 x 2 MiB
    unsigned short* wk = wq + (1u << 20);
    unsigned short* wv = wk + (1u << 20);
    unsigned short* wo = wv + (1u << 20);
    float* cosT = (float*)(w + (24u << 20));                        // 256 KiB
    float* sinT = cosT + SEQ * 32;
    unsigned long long* m64 = (unsigned long long*)(w + (24u << 20) + (1u << 19)); // 1 KiB
    unsigned short* Qb  = (unsigned short*)(w + (25u << 20));       // 3 x 16 MiB
    unsigned short* Kb  = Qb + (8u << 20);
    unsigned short* Vtb = Kb + (8u << 20);
    unsigned short* Ob  = xb;                                       // reuse x's slot

    prologue_kernel<<<dim3(6401), 256, 0, stream>>>(x, q_w, k_w, v_w, o_w,
                                                    xb, wq, wk, wv, wo,
                                                    cosT, sinT, mask, m64);

    gemm_qk<<<dim3(8, 64), 256, 0, stream>>>(xb, wq, wk, q_b, k_b, Qb, Kb, cosT, sinT);
    gemm_vt<<<dim3(8, 64), 256, 0, stream>>>(wv, xb, v_b, Vtb);

    attn_kernel<<<dim3(1024), 256, 0, stream>>>(Qb, Kb, Vtb, m64, Ob);

    gemm_bt<<<dim3(DIMN / 128, MROWS / 128), 256, 0, stream>>>(Ob, wo, o_b, out);
}